// Round 14
// baseline (1341.834 us; speedup 1.0000x reference)
//
#include <hip/hip_runtime.h>
#include <hip/hip_bf16.h>

#define DD 128
#define LL 8
#define MM 32768
#define NN (LL*MM)
#define GG 5
#define FF 2
#define SORT_STRIDE 33408   // 32768 + headroom (>= 5*31 pad)

typedef __attribute__((ext_vector_type(8))) short short8;
typedef __attribute__((ext_vector_type(4))) short short4v;
typedef __attribute__((ext_vector_type(4))) float f32x4;

#define MFMA16(a,b,c) __builtin_amdgcn_mfma_f32_16x16x32_bf16((a),(b),(c),0,0,0)
// Pin load-issue order: compiler cannot sink loads past a memory-clobber asm.
#define VMEM_FENCE() asm volatile("s_waitcnt vmcnt(0)" ::: "memory")

__device__ __forceinline__ short f2bf(float x){
  __hip_bfloat16 h = __float2bfloat16(x);
  return *reinterpret_cast<short*>(&h);
}

__device__ __forceinline__ short8 pack8(f32x4 a, f32x4 b){
  short8 r;
  r[0]=f2bf(a[0]); r[1]=f2bf(a[1]); r[2]=f2bf(a[2]); r[3]=f2bf(a[3]);
  r[4]=f2bf(b[0]); r[5]=f2bf(b[1]); r[6]=f2bf(b[2]); r[7]=f2bf(b[3]);
  return r;
}

// ---------------- one-time weight convert to fragment-contiguous bf16 ------
__global__ void prep_kernel(const float* __restrict__ hs_W, const float* __restrict__ W1,
                            const float* __restrict__ W2, const float* __restrict__ W3,
                            const float* __restrict__ Wi,
                            short* __restrict__ hsWt, short* __restrict__ W1t,
                            short* __restrict__ W2t, short* __restrict__ W3t,
                            short* __restrict__ Wit, int* __restrict__ cntcur)
{
  if (blockIdx.x == 0 && threadIdx.x < 70) cntcur[threadIdx.x] = 0;  // cnt[35]+cur[35]
  int u = blockIdx.x*256 + threadIdx.x;   // 75776 units of 8 k-elems
  const float* src; short* dst; int ldw;
  if (u < 4096){                                   // hsWt: ct8 kc8
    int i=u, ct=i>>9, kc=(i>>6)&7, ln=i&63;
    src = hs_W + (size_t)(kc*32 + 8*(ln>>4))*128 + ct*16 + (ln&15);
    dst = hsWt + (size_t)i*8; ldw=128;
  } else if (u < 24576){                           // W1t: 5 x (ct8 kc8)
    int v=u-4096, g=v>>12, i=v&4095, ct=i>>9, kc=(i>>6)&7, ln=i&63;
    src = W1 + (size_t)g*32768 + (size_t)(kc*32 + 8*(ln>>4))*128 + ct*16 + (ln&15);
    dst = W1t + (size_t)g*32768 + i*8; ldw=128;
  } else if (u < 34816){                           // W2t: 5 x (ct8 kc4)
    int v=u-24576, g=v>>11, i=v&2047, ct=i>>8, kc=(i>>6)&3, ln=i&63;
    src = W2 + (size_t)g*16384 + (size_t)(kc*32 + 8*(ln>>4))*128 + ct*16 + (ln&15);
    dst = W2t + (size_t)g*16384 + i*8; ldw=128;
  } else if (u < 45056){                           // W3t: 5 x (ct8 kc4)
    int v=u-34816, g=v>>11, i=v&2047, ct=i>>8, kc=(i>>6)&3, ln=i&63;
    src = W3 + (size_t)g*16384 + (size_t)(kc*32 + 8*(ln>>4))*128 + ct*16 + (ln&15);
    dst = W3t + (size_t)g*16384 + i*8; ldw=128;
  } else {                                         // Wit: 5 x (ct24 kc4)
    int v=u-45056, g=v/6144, i=v%6144, ct=i>>8, kc=(i>>6)&3, ln=i&63;
    src = Wi + (size_t)g*49152 + (size_t)(kc*32 + 8*(ln>>4))*384 + ct*16 + (ln&15);
    dst = Wit + (size_t)g*49152 + i*8; ldw=384;
  }
  short8 o;
#pragma unroll
  for (int j=0;j<8;++j) o[j] = f2bf(src[(size_t)j*ldw]);
  *(short8*)dst = o;
}

// ---------------- bucket sort by gate, per level ----------------
__global__ void count_kernel(const int* __restrict__ gate, int* __restrict__ cnt){
  __shared__ int lc[GG];
  const int li = blockIdx.x >> 7;
  const int m  = ((blockIdx.x & 127) << 8) + threadIdx.x;
  if (threadIdx.x < GG) lc[threadIdx.x] = 0;
  __syncthreads();
  int g = gate[(li+1)*MM + m];
  atomicAdd(&lc[g], 1);
  __syncthreads();
  if (threadIdx.x < GG && lc[threadIdx.x] > 0)
    atomicAdd(&cnt[li*GG + threadIdx.x], lc[threadIdx.x]);
}

__global__ void offs_kernel(const int* __restrict__ cnt, int* __restrict__ off,
                            int* __restrict__ pend, int* __restrict__ sorted){
  __shared__ int se[35], sp[35];
  const int tid = threadIdx.x;
  if (tid < LL-1){
    int l = tid, o = 0;
    for (int g = 0; g < GG; ++g){
      off[l*GG+g] = o;
      int c = cnt[l*GG+g];
      pend[l*GG+g] = o + c;
      se[l*GG+g] = o + c;
      o += ((c + 31) >> 5) << 5;          // pad each bucket to 32
      sp[l*GG+g] = o;
    }
  }
  __syncthreads();
  for (int b = 0; b < 35; ++b){
    int l = b / GG;
    for (int i = se[b] + tid; i < sp[b]; i += 256)
      sorted[l*SORT_STRIDE + i] = -1;
  }
}

__global__ void scatter_kernel(const int* __restrict__ gate, const int* __restrict__ off,
                               int* __restrict__ cur, int* __restrict__ sorted){
  __shared__ int lc[GG];
  __shared__ int base[GG];
  const int li = blockIdx.x >> 7;
  const int m  = ((blockIdx.x & 127) << 8) + threadIdx.x;
  if (threadIdx.x < GG) lc[threadIdx.x] = 0;
  __syncthreads();
  int g = gate[(li+1)*MM + m];
  int p = atomicAdd(&lc[g], 1);
  __syncthreads();
  if (threadIdx.x < GG)
    base[threadIdx.x] = atomicAdd(&cur[li*GG + threadIdx.x], lc[threadIdx.x]);
  __syncthreads();
  sorted[li*SORT_STRIDE + off[li*GG+g] + base[g] + p] = m;
}

// ---------------- hs = [s|t] @ hs_W + hs_b  (+ level-0 hf zero-fill) -------
__global__ __launch_bounds__(256,5) void hs_kernel(
    const float* __restrict__ s, const float* __restrict__ t,
    const short* __restrict__ Wt, const float* __restrict__ b,
    float* __restrict__ hs, short* __restrict__ hs_sh,
    float* __restrict__ hf, short* __restrict__ hf_sh)
{
  __shared__ __align__(16) short Xs[16384];      // 32768 B exactly
  const int tid=threadIdx.x, lane=tid&63, w=tid>>6;   // w = 0..3
  const int l15=lane&15, lq=lane>>4;
  const int row0 = blockIdx.x*64;

  // stage X rows into fragment layout — two pinned batches of 8
  {
    const int r = tid>>2, p = tid&3;
    const float* srow = s + (size_t)(row0+r)*DD;
    const float* trow = t + (size_t)(row0+r)*DD;
    const int rf = r>>4, rl = r&15;
#pragma unroll
    for (int h=0; h<2; ++h){
      f32x4 va[8];
#pragma unroll
      for (int i=0;i<4;++i){
        int u = p + 4*(4*h + i);
        const float* pp = (u<16) ? (srow + 8*u) : (trow + 8*(u-16));
        va[2*i]   = __builtin_nontemporal_load((const f32x4*)pp);
        va[2*i+1] = __builtin_nontemporal_load((const f32x4*)(pp+4));
      }
      VMEM_FENCE();
#pragma unroll
      for (int i=0;i<4;++i){
        int u = p + 4*(4*h + i);
        short8 v = pack8(va[2*i], va[2*i+1]);
        *(short8*)(Xs + ((rf*8+(u>>2))*64 + (u&3)*16 + rl)*8) = v;
      }
    }
  }

  // level-0 hf zero-fill (replaces memset nodes)
  if (row0 < MM){
    f32x4 zf4 = {0.f,0.f,0.f,0.f};
    short8 zs8 = {0,0,0,0,0,0,0,0};
    const size_t basei = (size_t)row0*DD;
    for (int i=tid; i<2048; i+=256)
      __builtin_nontemporal_store(zf4, (f32x4*)(hf + basei + i*4));
    for (int i=tid; i<1024; i+=256) *(short8*)(hf_sh + basei + i*8) = zs8;
  }
  __syncthreads();

  f32x4 zf = {0.f,0.f,0.f,0.f};
  f32x4 acc[4][2];
#pragma unroll
  for (int rr=0;rr<4;++rr){ acc[rr][0]=zf; acc[rr][1]=zf; }
  const short* Aw = Wt + (16*w)*512 + lane*8;
#pragma unroll
  for (int h=0; h<2; ++h){
    short8 af[8];
#pragma unroll
    for (int i=0;i<8;++i) af[i] = *(const short8*)(Aw + (8*h + i)*512);
    VMEM_FENCE();
#pragma unroll
    for (int kc=0;kc<8;++kc){
      short8 bx[4];
#pragma unroll
      for (int rr=0;rr<4;++rr)
        bx[rr] = *(const short8*)(Xs + ((rr*8 + kc)*64 + lane)*8);
#pragma unroll
      for (int rr=0;rr<4;++rr)
        acc[rr][h] = MFMA16(af[kc], bx[rr], acc[rr][h]);
    }
  }

  f32x4 bv0 = *(const f32x4*)(b + 32*w + 4*lq);
  f32x4 bv1 = *(const f32x4*)(b + 32*w + 16 + 4*lq);
#pragma unroll
  for (int rr=0;rr<4;++rr){
    int row = row0 + rr*16 + l15;
#pragma unroll
    for (int q=0;q<2;++q){
      f32x4 bv = q ? bv1 : bv0;
      int col = 32*w + 16*q + 4*lq;
      f32x4 o; short4v pk;
#pragma unroll
      for (int j=0;j<4;++j){ o[j] = acc[rr][q][j] + bv[j]; pk[j] = f2bf(o[j]); }
      __builtin_nontemporal_store(o, (f32x4*)(hs + (size_t)row*DD + col));
      *(short4v*)(hs_sh + (size_t)row*DD + col) = pk;
    }
  }
}

// ---------------- fused per-level kernel: 32 nodes/block, col-split --------
// REP: diagnostic repeat (idempotent).
__global__ __launch_bounds__(256,5) void level_kernel(
    int lvl, int REP, float* __restrict__ hfg,
    const short* __restrict__ hs_sh, short* __restrict__ hf_sh,
    const int* __restrict__ fanin,
    const short* __restrict__ W1t, const short* __restrict__ W2t,
    const short* __restrict__ W3t, const short* __restrict__ Wit,
    const float* __restrict__ b1, const float* __restrict__ b2,
    const float* __restrict__ b3, const float* __restrict__ bi,
    const float* __restrict__ bh,
    const int* __restrict__ off, const int* __restrict__ pend,
    const int* __restrict__ sorted)
{
  __shared__ __align__(16) short Xs[16384];      // 32768 B exactly
  const int tid=threadIdx.x, lane=tid&63, w=tid>>6;  // w = 0..3
  const int l15=lane&15, lq=lane>>4;
  const int li = lvl-1;
  const int pos0 = blockIdx.x*32;

  int g = -1;
#pragma unroll
  for (int q=0;q<GG;++q)
    if (pos0 >= off[li*GG+q] && pos0 < pend[li*GG+q]) g = q;
  if (g < 0) return;                              // uniform

  const int m0 = sorted[li*SORT_STRIDE + pos0 + l15];
  const int m1 = sorted[li*SORT_STRIDE + pos0 + 16 + l15];
  f32x4 zf = {0.f,0.f,0.f,0.f};

  for (int rp = 0; rp < REP; ++rp){
    // gather X rows into fragment layout
    {
      const int r = tid>>2, p = tid&3;
      const int mg = sorted[li*SORT_STRIDE + pos0 + (r>>1)];
      const int src = (mg>=0) ? li*MM + fanin[((size_t)li*MM+mg)*FF + (r&1)] : 0;
      const short* hsrow = hs_sh + (size_t)src*DD;
      const short* hfrow = hf_sh + (size_t)src*DD;
      const int rf = r>>4, rl = r&15;
      short8 va[8];
#pragma unroll
      for (int i=0;i<8;++i){
        int u = p + 4*i;
        va[i] = *(const short8*)((u<16) ? (hsrow + 8*u) : (hfrow + 8*(u-16)));
      }
      VMEM_FENCE();
#pragma unroll
      for (int i=0;i<8;++i){
        int u = p + 4*i;
        *(short8*)(Xs + ((rf*8+(u>>2))*64 + (u&3)*16 + rl)*8) = va[i];
      }
    }
    __syncthreads();                                // B1

    // ---- GEMM1: K=256, A in two pinned batches of 8 ----
    f32x4 acc[4][2];
#pragma unroll
    for (int rr=0;rr<4;++rr){ acc[rr][0]=zf; acc[rr][1]=zf; }
    {
      const short* A1w = W1t + (size_t)g*32768 + (16*w)*512 + lane*8;
#pragma unroll
      for (int h=0; h<2; ++h){
        short8 af[8];
#pragma unroll
        for (int i=0;i<8;++i) af[i] = *(const short8*)(A1w + (8*h + i)*512);
        VMEM_FENCE();
#pragma unroll
        for (int kc=0;kc<8;++kc){
          short8 bx[4];
#pragma unroll
          for (int rr=0;rr<4;++rr)
            bx[rr] = *(const short8*)(Xs + ((rr*8 + kc)*64 + lane)*8);
#pragma unroll
          for (int rr=0;rr<4;++rr)
            acc[rr][h] = MFMA16(af[kc], bx[rr], acc[rr][h]);
        }
      }
    }
    __syncthreads();                                // B2: all X reads done
    {
      f32x4 bv0 = *(const f32x4*)(b1 + g*DD + 32*w + 4*lq);
      f32x4 bv1 = *(const f32x4*)(b1 + g*DD + 32*w + 16 + 4*lq);
#pragma unroll
      for (int rr=0;rr<4;++rr){
#pragma unroll
        for (int q=0;q<2;++q){
          f32x4 bv = q ? bv1 : bv0;
          short4v pk;
#pragma unroll
          for (int j=0;j<4;++j) pk[j] = f2bf(fmaxf(acc[rr][q][j] + bv[j], 0.f));
          *(short4v*)(Xs + ((rr*4 + w)*64 + (2*q + (lq>>1))*16 + l15)*8 + 4*(lq&1)) = pk;
        }
      }
    }
    __syncthreads();                                // B3: H1 ready

    // ---- GEMM2: K=128 ----
    f32x4 acc2[4][2];
#pragma unroll
    for (int rr=0;rr<4;++rr){ acc2[rr][0]=zf; acc2[rr][1]=zf; }
    {
      const short* A2w = W2t + (size_t)g*16384 + (8*w)*512 + lane*8;
      short8 af[8];
#pragma unroll
      for (int i=0;i<8;++i) af[i] = *(const short8*)(A2w + i*512);
      VMEM_FENCE();
#pragma unroll
      for (int kc=0;kc<4;++kc){
        short8 bx[4];
#pragma unroll
        for (int rr=0;rr<4;++rr)
          bx[rr] = *(const short8*)(Xs + ((rr*4 + kc)*64 + lane)*8);
#pragma unroll
        for (int rr=0;rr<4;++rr){
          acc2[rr][0] = MFMA16(af[kc],   bx[rr], acc2[rr][0]);
          acc2[rr][1] = MFMA16(af[4+kc], bx[rr], acc2[rr][1]);
        }
      }
    }
    {
      f32x4 bv0 = *(const f32x4*)(b2 + g*DD + 32*w + 4*lq);
      f32x4 bv1 = *(const f32x4*)(b2 + g*DD + 32*w + 16 + 4*lq);
#pragma unroll
      for (int rr=0;rr<4;++rr){
#pragma unroll
        for (int q=0;q<2;++q){
          f32x4 bv = q ? bv1 : bv0;
          short4v pk;
#pragma unroll
          for (int j=0;j<4;++j) pk[j] = f2bf(fmaxf(acc2[rr][q][j] + bv[j], 0.f));
          *(short4v*)(Xs + 8192 + ((rr*4 + w)*64 + (2*q + (lq>>1))*16 + l15)*8 + 4*(lq&1)) = pk;
        }
      }
    }
    __syncthreads();                                // B4: H2 ready

    // ---- GEMM3: K=128 ----
    f32x4 acc3[4][2];
#pragma unroll
    for (int rr=0;rr<4;++rr){ acc3[rr][0]=zf; acc3[rr][1]=zf; }
    {
      const short* A3w = W3t + (size_t)g*16384 + (8*w)*512 + lane*8;
      short8 af[8];
#pragma unroll
      for (int i=0;i<8;++i) af[i] = *(const short8*)(A3w + i*512);
      VMEM_FENCE();
#pragma unroll
      for (int kc=0;kc<4;++kc){
        short8 bx[4];
#pragma unroll
        for (int rr=0;rr<4;++rr)
          bx[rr] = *(const short8*)(Xs + 8192 + ((rr*4 + kc)*64 + lane)*8);
#pragma unroll
        for (int rr=0;rr<4;++rr){
          acc3[rr][0] = MFMA16(af[kc],   bx[rr], acc3[rr][0]);
          acc3[rr][1] = MFMA16(af[4+kc], bx[rr], acc3[rr][1]);
        }
      }
    }
    // pair-sum over F -> msg into Xs[0:4096)
    {
      f32x4 bv0 = *(const f32x4*)(b3 + g*DD + 32*w + 4*lq);
      f32x4 bv1 = *(const f32x4*)(b3 + g*DD + 32*w + 16 + 4*lq);
#pragma unroll
      for (int rr=0;rr<4;++rr){
#pragma unroll
        for (int q=0;q<2;++q){
          f32x4 bv = q ? bv1 : bv0;
          f32x4 mv;
#pragma unroll
          for (int j=0;j<4;++j){
            float v = acc3[rr][q][j];
            mv[j] = v + __shfl_xor(v, 1) + 2.f*bv[j];
          }
          if ((l15 & 1) == 0){
            int n = rr*8 + (l15>>1);                 // node 0..31
            short4v pk;
#pragma unroll
            for (int j=0;j<4;++j) pk[j] = f2bf(mv[j]);
            *(short4v*)(Xs + (((n>>4)*4 + w)*64 + (2*q + (lq>>1))*16 + (n&15))*8 + 4*(lq&1)) = pk;
          }
        }
      }
    }
    __syncthreads();                                // B5: msg ready

    // ---- GRU: 2 q-passes ----
    const short* AW = Wit + (size_t)g*49152 + lane*8;
    const int lo = lvl*MM;
#pragma unroll
    for (int q=0;q<2;++q){
      short8 af[12];
#pragma unroll
      for (int kc=0;kc<4;++kc){
        int cti = ((2*w + q)*4 + kc)*512;
        af[kc]   = *(const short8*)(AW + cti);
        af[4+kc] = *(const short8*)(AW + 16384 + cti);
        af[8+kc] = *(const short8*)(AW + 32768 + cti);
      }
      VMEM_FENCE();
      f32x4 gr[2], gz[2], gn[2];
      gr[0]=zf; gr[1]=zf; gz[0]=zf; gz[1]=zf; gn[0]=zf; gn[1]=zf;
#pragma unroll
      for (int kc=0;kc<4;++kc){
#pragma unroll
        for (int rfm=0;rfm<2;++rfm){
          short8 bm = *(const short8*)(Xs + ((rfm*4 + kc)*64 + lane)*8);
          gr[rfm] = MFMA16(af[kc],   bm, gr[rfm]);
          gz[rfm] = MFMA16(af[4+kc], bm, gz[rfm]);
          gn[rfm] = MFMA16(af[8+kc], bm, gn[rfm]);
        }
      }
      int col = 32*w + 16*q + 4*lq;
      f32x4 biR = *(const f32x4*)(bi + g*384 + col);
      f32x4 biZ = *(const f32x4*)(bi + g*384 + 128 + col);
      f32x4 biN = *(const f32x4*)(bi + g*384 + 256 + col);
      f32x4 bhR = *(const f32x4*)(bh + g*384 + col);
      f32x4 bhZ = *(const f32x4*)(bh + g*384 + 128 + col);
      f32x4 bhN = *(const f32x4*)(bh + g*384 + 256 + col);
#pragma unroll
      for (int rfm=0;rfm<2;++rfm){
        int m = rfm ? m1 : m0;
        if (m < 0) continue;
        f32x4 o; short4v pk;
#pragma unroll
        for (int j=0;j<4;++j){
          float xr = gr[rfm][j] + biR[j] + bhR[j];
          float xz = gz[rfm][j] + biZ[j] + bhZ[j];
          float r_ = 1.f/(1.f + __expf(-xr));
          float z_ = 1.f/(1.f + __expf(-xz));
          float xn = gn[rfm][j] + biN[j] + r_*bhN[j];
          float n_ = 2.f/(1.f + __expf(-2.f*xn)) - 1.f;
          o[j] = (1.f - z_)*n_;
          pk[j] = f2bf(o[j]);
        }
        __builtin_nontemporal_store(o, (f32x4*)(hfg + (size_t)(lo + m)*DD + col));
        *(short4v*)(hf_sh + (size_t)(lo + m)*DD + col) = pk;
      }
    }
    __syncthreads();     // Xs safe to overwrite next rep
  }
}

extern "C" void kernel_launch(void* const* d_in, const int* in_sizes, int n_in,
                              void* d_out, int out_size, void* d_ws, size_t ws_size,
                              hipStream_t stream)
{
  const float* s    = (const float*)d_in[0];
  const float* t    = (const float*)d_in[1];
  const int*   gate = (const int*)d_in[2];
  const int*   fanin= (const int*)d_in[3];
  const float* hs_W = (const float*)d_in[4];
  const float* hs_b = (const float*)d_in[5];
  const float* W1   = (const float*)d_in[6];
  const float* b1   = (const float*)d_in[7];
  const float* W2   = (const float*)d_in[8];
  const float* b2   = (const float*)d_in[9];
  const float* W3   = (const float*)d_in[10];
  const float* b3   = (const float*)d_in[11];
  const float* Wi   = (const float*)d_in[12];
  // d_in[13] = gru_Wh: unused (hidden state is exactly zero)
  const float* bi   = (const float*)d_in[14];
  const float* bh   = (const float*)d_in[15];

  float* hs = (float*)d_out;
  float* hf = hs + (size_t)NN*DD;

  int* cnt    = (int*)d_ws;        // [7][5] ; cur right after
  int* cur    = cnt + 35;
  int* off    = cnt + 70;
  int* pendv  = cnt + 105;
  int* sorted = cnt + 256;         // 7*SORT_STRIDE ints, < 1 MB

  short* wbase = (short*)((char*)d_ws + (1<<20));
  short* hsWt = wbase;             // 4096*8
  short* W1t  = wbase + 32768;     // 5*32768
  short* W2t  = wbase + 196608;    // 5*16384
  short* W3t  = wbase + 278528;    // 5*16384
  short* Wit  = wbase + 360448;    // 5*49152

  short* hs_sh = (short*)((char*)d_ws + (size_t)(8<<20));   // [N][128] bf16
  short* hf_sh = hs_sh + (size_t)NN*DD;                      // [N][128] bf16

  prep_kernel<<<296, 256, 0, stream>>>(hs_W, W1, W2, W3, Wi,
                                       hsWt, W1t, W2t, W3t, Wit, cnt);
  count_kernel<<<896, 256, 0, stream>>>(gate, cnt);
  offs_kernel<<<1, 256, 0, stream>>>(cnt, off, pendv, sorted);
  scatter_kernel<<<896, 256, 0, stream>>>(gate, off, cur, sorted);
  hs_kernel<<<NN/64, 256, 0, stream>>>(s, t, hsWt, hs_b, hs, hs_sh, hf, hf_sh);
  // DIAGNOSTIC: REP=15 on level 4 only — lifts that dispatch above the
  // ~161us poison fills AND the ~135us hs into rocprof's top-5.
  for (int lvl = 1; lvl < LL; ++lvl){
    level_kernel<<<SORT_STRIDE/32, 256, 0, stream>>>(lvl, (lvl==4)?15:1, hf,
        hs_sh, hf_sh, fanin, W1t, W2t, W3t, Wit,
        b1, b2, b3, bi, bh, off, pendv, sorted);
  }
}

// Round 15
// 449.633 us; speedup vs baseline: 2.9843x; 2.9843x over previous
//
#include <hip/hip_runtime.h>
#include <hip/hip_bf16.h>

#define DD 128
#define LL 8
#define MM 32768
#define NN (LL*MM)
#define GG 5
#define FF 2
#define SORT_STRIDE 33408   // 32768 + headroom (>= 5*31 pad)

typedef __attribute__((ext_vector_type(8))) short short8;
typedef __attribute__((ext_vector_type(4))) short short4v;
typedef __attribute__((ext_vector_type(4))) float f32x4;

#define MFMA16(a,b,c) __builtin_amdgcn_mfma_f32_16x16x32_bf16((a),(b),(c),0,0,0)
#define VMEM_FENCE() asm volatile("s_waitcnt vmcnt(0)" ::: "memory")

__device__ __forceinline__ short f2bf(float x){
  __hip_bfloat16 h = __float2bfloat16(x);
  return *reinterpret_cast<short*>(&h);
}

__device__ __forceinline__ short8 pack8(f32x4 a, f32x4 b){
  short8 r;
  r[0]=f2bf(a[0]); r[1]=f2bf(a[1]); r[2]=f2bf(a[2]); r[3]=f2bf(a[3]);
  r[4]=f2bf(b[0]); r[5]=f2bf(b[1]); r[6]=f2bf(b[2]); r[7]=f2bf(b[3]);
  return r;
}

// ---------------- one-time weight convert to fragment-contiguous bf16 ------
__global__ void prep_kernel(const float* __restrict__ hs_W, const float* __restrict__ W1,
                            const float* __restrict__ W2, const float* __restrict__ W3,
                            const float* __restrict__ Wi,
                            short* __restrict__ hsWt, short* __restrict__ W1t,
                            short* __restrict__ W2t, short* __restrict__ W3t,
                            short* __restrict__ Wit, int* __restrict__ cntcur)
{
  if (blockIdx.x == 0 && threadIdx.x < 70) cntcur[threadIdx.x] = 0;  // cnt[35]+cur[35]
  int u = blockIdx.x*256 + threadIdx.x;   // 75776 units of 8 k-elems
  const float* src; short* dst; int ldw;
  if (u < 4096){                                   // hsWt: ct8 kc8
    int i=u, ct=i>>9, kc=(i>>6)&7, ln=i&63;
    src = hs_W + (size_t)(kc*32 + 8*(ln>>4))*128 + ct*16 + (ln&15);
    dst = hsWt + (size_t)i*8; ldw=128;
  } else if (u < 24576){                           // W1t: 5 x (ct8 kc8)
    int v=u-4096, g=v>>12, i=v&4095, ct=i>>9, kc=(i>>6)&7, ln=i&63;
    src = W1 + (size_t)g*32768 + (size_t)(kc*32 + 8*(ln>>4))*128 + ct*16 + (ln&15);
    dst = W1t + (size_t)g*32768 + i*8; ldw=128;
  } else if (u < 34816){                           // W2t: 5 x (ct8 kc4)
    int v=u-24576, g=v>>11, i=v&2047, ct=i>>8, kc=(i>>6)&3, ln=i&63;
    src = W2 + (size_t)g*16384 + (size_t)(kc*32 + 8*(ln>>4))*128 + ct*16 + (ln&15);
    dst = W2t + (size_t)g*16384 + i*8; ldw=128;
  } else if (u < 45056){                           // W3t: 5 x (ct8 kc4)
    int v=u-34816, g=v>>11, i=v&2047, ct=i>>8, kc=(i>>6)&3, ln=i&63;
    src = W3 + (size_t)g*16384 + (size_t)(kc*32 + 8*(ln>>4))*128 + ct*16 + (ln&15);
    dst = W3t + (size_t)g*16384 + i*8; ldw=128;
  } else {                                         // Wit: 5 x (ct24 kc4)
    int v=u-45056, g=v/6144, i=v%6144, ct=i>>8, kc=(i>>6)&3, ln=i&63;
    src = Wi + (size_t)g*49152 + (size_t)(kc*32 + 8*(ln>>4))*384 + ct*16 + (ln&15);
    dst = Wit + (size_t)g*49152 + i*8; ldw=384;
  }
  short8 o;
#pragma unroll
  for (int j=0;j<8;++j) o[j] = f2bf(src[(size_t)j*ldw]);
  *(short8*)dst = o;
}

// ---------------- bucket sort by gate, per level ----------------
__global__ void count_kernel(const int* __restrict__ gate, int* __restrict__ cnt){
  __shared__ int lc[GG];
  const int li = blockIdx.x >> 7;
  const int m  = ((blockIdx.x & 127) << 8) + threadIdx.x;
  if (threadIdx.x < GG) lc[threadIdx.x] = 0;
  __syncthreads();
  int g = gate[(li+1)*MM + m];
  atomicAdd(&lc[g], 1);
  __syncthreads();
  if (threadIdx.x < GG && lc[threadIdx.x] > 0)
    atomicAdd(&cnt[li*GG + threadIdx.x], lc[threadIdx.x]);
}

__global__ void offs_kernel(const int* __restrict__ cnt, int* __restrict__ off,
                            int* __restrict__ pend, int* __restrict__ sorted){
  __shared__ int se[35], sp[35];
  const int tid = threadIdx.x;
  if (tid < LL-1){
    int l = tid, o = 0;
    for (int g = 0; g < GG; ++g){
      off[l*GG+g] = o;
      int c = cnt[l*GG+g];
      pend[l*GG+g] = o + c;
      se[l*GG+g] = o + c;
      o += ((c + 31) >> 5) << 5;          // pad each bucket to 32
      sp[l*GG+g] = o;
    }
  }
  __syncthreads();
  for (int b = 0; b < 35; ++b){
    int l = b / GG;
    for (int i = se[b] + tid; i < sp[b]; i += 256)
      sorted[l*SORT_STRIDE + i] = -1;
  }
}

__global__ void scatter_kernel(const int* __restrict__ gate, const int* __restrict__ off,
                               int* __restrict__ cur, int* __restrict__ sorted){
  __shared__ int lc[GG];
  __shared__ int base[GG];
  const int li = blockIdx.x >> 7;
  const int m  = ((blockIdx.x & 127) << 8) + threadIdx.x;
  if (threadIdx.x < GG) lc[threadIdx.x] = 0;
  __syncthreads();
  int g = gate[(li+1)*MM + m];
  int p = atomicAdd(&lc[g], 1);
  __syncthreads();
  if (threadIdx.x < GG)
    base[threadIdx.x] = atomicAdd(&cur[li*GG + threadIdx.x], lc[threadIdx.x]);
  __syncthreads();
  sorted[li*SORT_STRIDE + off[li*GG+g] + base[g] + p] = m;
}

// ---------------- hs = [s|t] @ hs_W + hs_b  (+ level-0 zero-fills) ---------
// Shadow is INTERLEAVED: xsh[node][256] = [hs bf16 x128 | hf bf16 x128].
__global__ __launch_bounds__(256,5) void hs_kernel(
    const float* __restrict__ s, const float* __restrict__ t,
    const short* __restrict__ Wt, const float* __restrict__ b,
    float* __restrict__ hs, short* __restrict__ xsh,
    float* __restrict__ hf)
{
  __shared__ __align__(16) short Xs[16384];      // 32768 B exactly
  const int tid=threadIdx.x, lane=tid&63, w=tid>>6;   // w = 0..3
  const int l15=lane&15, lq=lane>>4;
  const int row0 = blockIdx.x*64;

  // stage X rows into fragment layout — two pinned batches of 8
  {
    const int r = tid>>2, p = tid&3;
    const float* srow = s + (size_t)(row0+r)*DD;
    const float* trow = t + (size_t)(row0+r)*DD;
    const int rf = r>>4, rl = r&15;
#pragma unroll
    for (int h=0; h<2; ++h){
      f32x4 va[8];
#pragma unroll
      for (int i=0;i<4;++i){
        int u = p + 4*(4*h + i);
        const float* pp = (u<16) ? (srow + 8*u) : (trow + 8*(u-16));
        va[2*i]   = __builtin_nontemporal_load((const f32x4*)pp);
        va[2*i+1] = __builtin_nontemporal_load((const f32x4*)(pp+4));
      }
      VMEM_FENCE();
#pragma unroll
      for (int i=0;i<4;++i){
        int u = p + 4*(4*h + i);
        short8 v = pack8(va[2*i], va[2*i+1]);
        *(short8*)(Xs + ((rf*8+(u>>2))*64 + (u&3)*16 + rl)*8) = v;
      }
    }
  }

  // level-0 zero-fills: hf f32 output + xsh hf-half
  if (row0 < MM){
    f32x4 zf4 = {0.f,0.f,0.f,0.f};
    short8 zs8 = {0,0,0,0,0,0,0,0};
    const size_t basei = (size_t)row0*DD;
    for (int i=tid; i<2048; i+=256)
      __builtin_nontemporal_store(zf4, (f32x4*)(hf + basei + i*4));
    for (int i=tid; i<1024; i+=256)
      __builtin_nontemporal_store(zs8,
        (short8*)(xsh + ((size_t)row0 + (i>>4))*256 + 128 + (i&15)*8));
  }
  __syncthreads();

  f32x4 zf = {0.f,0.f,0.f,0.f};
  f32x4 acc[4][2];
#pragma unroll
  for (int rr=0;rr<4;++rr){ acc[rr][0]=zf; acc[rr][1]=zf; }
  const short* Aw = Wt + (16*w)*512 + lane*8;
#pragma unroll
  for (int h=0; h<2; ++h){
    short8 af[8];
#pragma unroll
    for (int i=0;i<8;++i) af[i] = *(const short8*)(Aw + (8*h + i)*512);
    VMEM_FENCE();
#pragma unroll
    for (int kc=0;kc<8;++kc){
      short8 bx[4];
#pragma unroll
      for (int rr=0;rr<4;++rr)
        bx[rr] = *(const short8*)(Xs + ((rr*8 + kc)*64 + lane)*8);
#pragma unroll
      for (int rr=0;rr<4;++rr)
        acc[rr][h] = MFMA16(af[kc], bx[rr], acc[rr][h]);
    }
  }

  f32x4 bv0 = *(const f32x4*)(b + 32*w + 4*lq);
  f32x4 bv1 = *(const f32x4*)(b + 32*w + 16 + 4*lq);
#pragma unroll
  for (int rr=0;rr<4;++rr){
    int row = row0 + rr*16 + l15;
#pragma unroll
    for (int q=0;q<2;++q){
      f32x4 bv = q ? bv1 : bv0;
      int col = 32*w + 16*q + 4*lq;
      f32x4 o; short4v pk;
#pragma unroll
      for (int j=0;j<4;++j){ o[j] = acc[rr][q][j] + bv[j]; pk[j] = f2bf(o[j]); }
      __builtin_nontemporal_store(o, (f32x4*)(hs + (size_t)row*DD + col));
      __builtin_nontemporal_store(pk, (short4v*)(xsh + (size_t)row*256 + col));
    }
  }
}

// ---------------- fused per-level kernel: 32 nodes/block, col-split --------
// Gather reads ONE contiguous 512B row from interleaved xsh (nt loads, no
// L2 pollution -> weights stay L2-resident). lvl==1 skips the hf half (==0).
__global__ __launch_bounds__(256,5) void level_kernel(
    int lvl, float* __restrict__ hfg, short* __restrict__ xsh,
    const int* __restrict__ fanin,
    const short* __restrict__ W1t, const short* __restrict__ W2t,
    const short* __restrict__ W3t, const short* __restrict__ Wit,
    const float* __restrict__ b1, const float* __restrict__ b2,
    const float* __restrict__ b3, const float* __restrict__ bi,
    const float* __restrict__ bh,
    const int* __restrict__ off, const int* __restrict__ pend,
    const int* __restrict__ sorted)
{
  __shared__ __align__(16) short Xs[16384];      // 32768 B exactly
  const int tid=threadIdx.x, lane=tid&63, w=tid>>6;  // w = 0..3
  const int l15=lane&15, lq=lane>>4;
  const int li = lvl-1;
  const int pos0 = blockIdx.x*32;

  int g = -1;
#pragma unroll
  for (int q=0;q<GG;++q)
    if (pos0 >= off[li*GG+q] && pos0 < pend[li*GG+q]) g = q;
  if (g < 0) return;                              // uniform

  const int m0 = sorted[li*SORT_STRIDE + pos0 + l15];
  const int m1 = sorted[li*SORT_STRIDE + pos0 + 16 + l15];
  f32x4 zf = {0.f,0.f,0.f,0.f};

  // gather X rows (contiguous 512B per src row) into fragment layout
  {
    const int r = tid>>2, p = tid&3;
    const int mg = sorted[li*SORT_STRIDE + pos0 + (r>>1)];
    const int src = (mg>=0) ? li*MM + fanin[((size_t)li*MM+mg)*FF + (r&1)] : 0;
    const short* xrow = xsh + (size_t)src*256;
    const int rf = r>>4, rl = r&15;
    const bool lvl1 = (lvl == 1);
    short8 va[8];
    short8 zs8 = {0,0,0,0,0,0,0,0};
#pragma unroll
    for (int i=0;i<8;++i){
      int u = p + 4*i;
      va[i] = (lvl1 && u >= 16) ? zs8
            : __builtin_nontemporal_load((const short8*)(xrow + 8*u));
    }
    VMEM_FENCE();
#pragma unroll
    for (int i=0;i<8;++i){
      int u = p + 4*i;
      *(short8*)(Xs + ((rf*8+(u>>2))*64 + (u&3)*16 + rl)*8) = va[i];
    }
  }
  __syncthreads();                                // B1

  // ---- GEMM1: K=256, A in two pinned batches of 8 ----
  f32x4 acc[4][2];
#pragma unroll
  for (int rr=0;rr<4;++rr){ acc[rr][0]=zf; acc[rr][1]=zf; }
  {
    const short* A1w = W1t + (size_t)g*32768 + (16*w)*512 + lane*8;
#pragma unroll
    for (int h=0; h<2; ++h){
      short8 af[8];
#pragma unroll
      for (int i=0;i<8;++i) af[i] = *(const short8*)(A1w + (8*h + i)*512);
      VMEM_FENCE();
#pragma unroll
      for (int kc=0;kc<8;++kc){
        short8 bx[4];
#pragma unroll
        for (int rr=0;rr<4;++rr)
          bx[rr] = *(const short8*)(Xs + ((rr*8 + kc)*64 + lane)*8);
#pragma unroll
        for (int rr=0;rr<4;++rr)
          acc[rr][h] = MFMA16(af[kc], bx[rr], acc[rr][h]);
      }
    }
  }
  __syncthreads();                                // B2: all X reads done
  {
    f32x4 bv0 = *(const f32x4*)(b1 + g*DD + 32*w + 4*lq);
    f32x4 bv1 = *(const f32x4*)(b1 + g*DD + 32*w + 16 + 4*lq);
#pragma unroll
    for (int rr=0;rr<4;++rr){
#pragma unroll
      for (int q=0;q<2;++q){
        f32x4 bv = q ? bv1 : bv0;
        short4v pk;
#pragma unroll
        for (int j=0;j<4;++j) pk[j] = f2bf(fmaxf(acc[rr][q][j] + bv[j], 0.f));
        *(short4v*)(Xs + ((rr*4 + w)*64 + (2*q + (lq>>1))*16 + l15)*8 + 4*(lq&1)) = pk;
      }
    }
  }
  __syncthreads();                                // B3: H1 ready

  // ---- GEMM2: K=128 ----
  f32x4 acc2[4][2];
#pragma unroll
  for (int rr=0;rr<4;++rr){ acc2[rr][0]=zf; acc2[rr][1]=zf; }
  {
    const short* A2w = W2t + (size_t)g*16384 + (8*w)*512 + lane*8;
    short8 af[8];
#pragma unroll
    for (int i=0;i<8;++i) af[i] = *(const short8*)(A2w + i*512);
    VMEM_FENCE();
#pragma unroll
    for (int kc=0;kc<4;++kc){
      short8 bx[4];
#pragma unroll
      for (int rr=0;rr<4;++rr)
        bx[rr] = *(const short8*)(Xs + ((rr*4 + kc)*64 + lane)*8);
#pragma unroll
      for (int rr=0;rr<4;++rr){
        acc2[rr][0] = MFMA16(af[kc],   bx[rr], acc2[rr][0]);
        acc2[rr][1] = MFMA16(af[4+kc], bx[rr], acc2[rr][1]);
      }
    }
  }
  {
    f32x4 bv0 = *(const f32x4*)(b2 + g*DD + 32*w + 4*lq);
    f32x4 bv1 = *(const f32x4*)(b2 + g*DD + 32*w + 16 + 4*lq);
#pragma unroll
    for (int rr=0;rr<4;++rr){
#pragma unroll
      for (int q=0;q<2;++q){
        f32x4 bv = q ? bv1 : bv0;
        short4v pk;
#pragma unroll
        for (int j=0;j<4;++j) pk[j] = f2bf(fmaxf(acc2[rr][q][j] + bv[j], 0.f));
        *(short4v*)(Xs + 8192 + ((rr*4 + w)*64 + (2*q + (lq>>1))*16 + l15)*8 + 4*(lq&1)) = pk;
      }
    }
  }
  __syncthreads();                                // B4: H2 ready

  // ---- GEMM3: K=128 ----
  f32x4 acc3[4][2];
#pragma unroll
  for (int rr=0;rr<4;++rr){ acc3[rr][0]=zf; acc3[rr][1]=zf; }
  {
    const short* A3w = W3t + (size_t)g*16384 + (8*w)*512 + lane*8;
    short8 af[8];
#pragma unroll
    for (int i=0;i<8;++i) af[i] = *(const short8*)(A3w + i*512);
    VMEM_FENCE();
#pragma unroll
    for (int kc=0;kc<4;++kc){
      short8 bx[4];
#pragma unroll
      for (int rr=0;rr<4;++rr)
        bx[rr] = *(const short8*)(Xs + 8192 + ((rr*4 + kc)*64 + lane)*8);
#pragma unroll
      for (int rr=0;rr<4;++rr){
        acc3[rr][0] = MFMA16(af[kc],   bx[rr], acc3[rr][0]);
        acc3[rr][1] = MFMA16(af[4+kc], bx[rr], acc3[rr][1]);
      }
    }
  }
  // pair-sum over F -> msg into Xs[0:4096)
  {
    f32x4 bv0 = *(const f32x4*)(b3 + g*DD + 32*w + 4*lq);
    f32x4 bv1 = *(const f32x4*)(b3 + g*DD + 32*w + 16 + 4*lq);
#pragma unroll
    for (int rr=0;rr<4;++rr){
#pragma unroll
      for (int q=0;q<2;++q){
        f32x4 bv = q ? bv1 : bv0;
        f32x4 mv;
#pragma unroll
        for (int j=0;j<4;++j){
          float v = acc3[rr][q][j];
          mv[j] = v + __shfl_xor(v, 1) + 2.f*bv[j];
        }
        if ((l15 & 1) == 0){
          int n = rr*8 + (l15>>1);                 // node 0..31
          short4v pk;
#pragma unroll
          for (int j=0;j<4;++j) pk[j] = f2bf(mv[j]);
          *(short4v*)(Xs + (((n>>4)*4 + w)*64 + (2*q + (lq>>1))*16 + (n&15))*8 + 4*(lq&1)) = pk;
        }
      }
    }
  }
  __syncthreads();                                // B5: msg ready

  // ---- GRU: gi = msg(32x128) @ Wi[g]; h==0 so gh==bh. 2 q-passes ----
  const short* AW = Wit + (size_t)g*49152 + lane*8;
  const int lo = lvl*MM;
#pragma unroll
  for (int q=0;q<2;++q){
    short8 af[12];
#pragma unroll
    for (int kc=0;kc<4;++kc){
      int cti = ((2*w + q)*4 + kc)*512;
      af[kc]   = *(const short8*)(AW + cti);
      af[4+kc] = *(const short8*)(AW + 16384 + cti);
      af[8+kc] = *(const short8*)(AW + 32768 + cti);
    }
    VMEM_FENCE();
    f32x4 gr[2], gz[2], gn[2];
    gr[0]=zf; gr[1]=zf; gz[0]=zf; gz[1]=zf; gn[0]=zf; gn[1]=zf;
#pragma unroll
    for (int kc=0;kc<4;++kc){
#pragma unroll
      for (int rfm=0;rfm<2;++rfm){
        short8 bm = *(const short8*)(Xs + ((rfm*4 + kc)*64 + lane)*8);
        gr[rfm] = MFMA16(af[kc],   bm, gr[rfm]);
        gz[rfm] = MFMA16(af[4+kc], bm, gz[rfm]);
        gn[rfm] = MFMA16(af[8+kc], bm, gn[rfm]);
      }
    }
    int col = 32*w + 16*q + 4*lq;
    f32x4 biR = *(const f32x4*)(bi + g*384 + col);
    f32x4 biZ = *(const f32x4*)(bi + g*384 + 128 + col);
    f32x4 biN = *(const f32x4*)(bi + g*384 + 256 + col);
    f32x4 bhR = *(const f32x4*)(bh + g*384 + col);
    f32x4 bhZ = *(const f32x4*)(bh + g*384 + 128 + col);
    f32x4 bhN = *(const f32x4*)(bh + g*384 + 256 + col);
#pragma unroll
    for (int rfm=0;rfm<2;++rfm){
      int m = rfm ? m1 : m0;
      if (m < 0) continue;
      f32x4 o; short4v pk;
#pragma unroll
      for (int j=0;j<4;++j){
        float xr = gr[rfm][j] + biR[j] + bhR[j];
        float xz = gz[rfm][j] + biZ[j] + bhZ[j];
        float r_ = 1.f/(1.f + __expf(-xr));
        float z_ = 1.f/(1.f + __expf(-xz));
        float xn = gn[rfm][j] + biN[j] + r_*bhN[j];
        float n_ = 2.f/(1.f + __expf(-2.f*xn)) - 1.f;
        o[j] = (1.f - z_)*n_;
        pk[j] = f2bf(o[j]);
      }
      __builtin_nontemporal_store(o, (f32x4*)(hfg + (size_t)(lo + m)*DD + col));
      __builtin_nontemporal_store(pk,
        (short4v*)(xsh + (size_t)(lo + m)*256 + 128 + col));
    }
  }
}

extern "C" void kernel_launch(void* const* d_in, const int* in_sizes, int n_in,
                              void* d_out, int out_size, void* d_ws, size_t ws_size,
                              hipStream_t stream)
{
  const float* s    = (const float*)d_in[0];
  const float* t    = (const float*)d_in[1];
  const int*   gate = (const int*)d_in[2];
  const int*   fanin= (const int*)d_in[3];
  const float* hs_W = (const float*)d_in[4];
  const float* hs_b = (const float*)d_in[5];
  const float* W1   = (const float*)d_in[6];
  const float* b1   = (const float*)d_in[7];
  const float* W2   = (const float*)d_in[8];
  const float* b2   = (const float*)d_in[9];
  const float* W3   = (const float*)d_in[10];
  const float* b3   = (const float*)d_in[11];
  const float* Wi   = (const float*)d_in[12];
  // d_in[13] = gru_Wh: unused (hidden state is exactly zero)
  const float* bi   = (const float*)d_in[14];
  const float* bh   = (const float*)d_in[15];

  float* hs = (float*)d_out;
  float* hf = hs + (size_t)NN*DD;

  int* cnt    = (int*)d_ws;        // [7][5] ; cur right after
  int* cur    = cnt + 35;
  int* off    = cnt + 70;
  int* pendv  = cnt + 105;
  int* sorted = cnt + 256;         // 7*SORT_STRIDE ints, < 1 MB

  short* wbase = (short*)((char*)d_ws + (1<<20));
  short* hsWt = wbase;             // 4096*8
  short* W1t  = wbase + 32768;     // 5*32768
  short* W2t  = wbase + 196608;    // 5*16384
  short* W3t  = wbase + 278528;    // 5*16384
  short* Wit  = wbase + 360448;    // 5*49152

  // interleaved shadow: xsh[node][256] = [hs bf16 x128 | hf bf16 x128], 128MB
  short* xsh = (short*)((char*)d_ws + (size_t)(8<<20));

  prep_kernel<<<296, 256, 0, stream>>>(hs_W, W1, W2, W3, Wi,
                                       hsWt, W1t, W2t, W3t, Wit, cnt);
  count_kernel<<<896, 256, 0, stream>>>(gate, cnt);
  offs_kernel<<<1, 256, 0, stream>>>(cnt, off, pendv, sorted);
  scatter_kernel<<<896, 256, 0, stream>>>(gate, off, cur, sorted);
  hs_kernel<<<NN/64, 256, 0, stream>>>(s, t, hsWt, hs_b, hs, xsh, hf);
  for (int lvl = 1; lvl < LL; ++lvl){
    level_kernel<<<SORT_STRIDE/32, 256, 0, stream>>>(lvl, hf, xsh,
        fanin, W1t, W2t, W3t, Wit,
        b1, b2, b3, bi, bh, off, pendv, sorted);
  }
}

// Round 16
// 378.492 us; speedup vs baseline: 3.5452x; 1.1880x over previous
//
#include <hip/hip_runtime.h>
#include <hip/hip_bf16.h>

#define DD 128
#define LL 8
#define MM 32768
#define NN (LL*MM)
#define GG 5
#define FF 2
#define SORT_STRIDE 33408   // 32768 + headroom (>= 5*31 pad)

typedef __attribute__((ext_vector_type(8))) short short8;
typedef __attribute__((ext_vector_type(4))) short short4v;
typedef __attribute__((ext_vector_type(4))) float f32x4;

#define MFMA16(a,b,c) __builtin_amdgcn_mfma_f32_16x16x32_bf16((a),(b),(c),0,0,0)
#define VMEM_FENCE() asm volatile("s_waitcnt vmcnt(0)" ::: "memory")

__device__ __forceinline__ short f2bf(float x){
  __hip_bfloat16 h = __float2bfloat16(x);
  return *reinterpret_cast<short*>(&h);
}

__device__ __forceinline__ short8 pack8(f32x4 a, f32x4 b){
  short8 r;
  r[0]=f2bf(a[0]); r[1]=f2bf(a[1]); r[2]=f2bf(a[2]); r[3]=f2bf(a[3]);
  r[4]=f2bf(b[0]); r[5]=f2bf(b[1]); r[6]=f2bf(b[2]); r[7]=f2bf(b[3]);
  return r;
}

// ---------------- one-time weight convert to fragment-contiguous bf16 ------
__global__ void prep_kernel(const float* __restrict__ hs_W, const float* __restrict__ W1,
                            const float* __restrict__ W2, const float* __restrict__ W3,
                            const float* __restrict__ Wi,
                            short* __restrict__ hsWt, short* __restrict__ W1t,
                            short* __restrict__ W2t, short* __restrict__ W3t,
                            short* __restrict__ Wit, int* __restrict__ cntcur)
{
  if (blockIdx.x == 0 && threadIdx.x < 70) cntcur[threadIdx.x] = 0;  // cnt[35]+cur[35]
  int u = blockIdx.x*256 + threadIdx.x;   // 75776 units of 8 k-elems
  const float* src; short* dst; int ldw;
  if (u < 4096){                                   // hsWt: ct8 kc8
    int i=u, ct=i>>9, kc=(i>>6)&7, ln=i&63;
    src = hs_W + (size_t)(kc*32 + 8*(ln>>4))*128 + ct*16 + (ln&15);
    dst = hsWt + (size_t)i*8; ldw=128;
  } else if (u < 24576){                           // W1t: 5 x (ct8 kc8)
    int v=u-4096, g=v>>12, i=v&4095, ct=i>>9, kc=(i>>6)&7, ln=i&63;
    src = W1 + (size_t)g*32768 + (size_t)(kc*32 + 8*(ln>>4))*128 + ct*16 + (ln&15);
    dst = W1t + (size_t)g*32768 + i*8; ldw=128;
  } else if (u < 34816){                           // W2t: 5 x (ct8 kc4)
    int v=u-24576, g=v>>11, i=v&2047, ct=i>>8, kc=(i>>6)&3, ln=i&63;
    src = W2 + (size_t)g*16384 + (size_t)(kc*32 + 8*(ln>>4))*128 + ct*16 + (ln&15);
    dst = W2t + (size_t)g*16384 + i*8; ldw=128;
  } else if (u < 45056){                           // W3t: 5 x (ct8 kc4)
    int v=u-34816, g=v>>11, i=v&2047, ct=i>>8, kc=(i>>6)&3, ln=i&63;
    src = W3 + (size_t)g*16384 + (size_t)(kc*32 + 8*(ln>>4))*128 + ct*16 + (ln&15);
    dst = W3t + (size_t)g*16384 + i*8; ldw=128;
  } else {                                         // Wit: 5 x (ct24 kc4)
    int v=u-45056, g=v/6144, i=v%6144, ct=i>>8, kc=(i>>6)&3, ln=i&63;
    src = Wi + (size_t)g*49152 + (size_t)(kc*32 + 8*(ln>>4))*384 + ct*16 + (ln&15);
    dst = Wit + (size_t)g*49152 + i*8; ldw=384;
  }
  short8 o;
#pragma unroll
  for (int j=0;j<8;++j) o[j] = f2bf(src[(size_t)j*ldw]);
  *(short8*)dst = o;
}

// ---------------- bucket sort by gate, per level ----------------
__global__ void count_kernel(const int* __restrict__ gate, int* __restrict__ cnt){
  __shared__ int lc[GG];
  const int li = blockIdx.x >> 7;
  const int m  = ((blockIdx.x & 127) << 8) + threadIdx.x;
  if (threadIdx.x < GG) lc[threadIdx.x] = 0;
  __syncthreads();
  int g = gate[(li+1)*MM + m];
  atomicAdd(&lc[g], 1);
  __syncthreads();
  if (threadIdx.x < GG && lc[threadIdx.x] > 0)
    atomicAdd(&cnt[li*GG + threadIdx.x], lc[threadIdx.x]);
}

__global__ void offs_kernel(const int* __restrict__ cnt, int* __restrict__ off,
                            int* __restrict__ pend, int* __restrict__ sorted){
  __shared__ int se[35], sp[35];
  const int tid = threadIdx.x;
  if (tid < LL-1){
    int l = tid, o = 0;
    for (int g = 0; g < GG; ++g){
      off[l*GG+g] = o;
      int c = cnt[l*GG+g];
      pend[l*GG+g] = o + c;
      se[l*GG+g] = o + c;
      o += ((c + 31) >> 5) << 5;          // pad each bucket to 32
      sp[l*GG+g] = o;
    }
  }
  __syncthreads();
  for (int b = 0; b < 35; ++b){
    int l = b / GG;
    for (int i = se[b] + tid; i < sp[b]; i += 256)
      sorted[l*SORT_STRIDE + i] = -1;
  }
}

__global__ void scatter_kernel(const int* __restrict__ gate, const int* __restrict__ off,
                               int* __restrict__ cur, int* __restrict__ sorted){
  __shared__ int lc[GG];
  __shared__ int base[GG];
  const int li = blockIdx.x >> 7;
  const int m  = ((blockIdx.x & 127) << 8) + threadIdx.x;
  if (threadIdx.x < GG) lc[threadIdx.x] = 0;
  __syncthreads();
  int g = gate[(li+1)*MM + m];
  int p = atomicAdd(&lc[g], 1);
  __syncthreads();
  if (threadIdx.x < GG)
    base[threadIdx.x] = atomicAdd(&cur[li*GG + threadIdx.x], lc[threadIdx.x]);
  __syncthreads();
  sorted[li*SORT_STRIDE + off[li*GG+g] + base[g] + p] = m;
}

// ---------------- hs = [s|t] @ hs_W + hs_b  (+ level-0 zero-fills) ---------
// Shadow is INTERLEAVED: xsh[node][256] = [hs bf16 x128 | hf bf16 x128].
// nt only on the write-only f32 streams and the read-once s/t inputs.
__global__ __launch_bounds__(256,5) void hs_kernel(
    const float* __restrict__ s, const float* __restrict__ t,
    const short* __restrict__ Wt, const float* __restrict__ b,
    float* __restrict__ hs, short* __restrict__ xsh,
    float* __restrict__ hf)
{
  __shared__ __align__(16) short Xs[16384];      // 32768 B exactly
  const int tid=threadIdx.x, lane=tid&63, w=tid>>6;   // w = 0..3
  const int l15=lane&15, lq=lane>>4;
  const int row0 = blockIdx.x*64;

  // stage X rows into fragment layout — two pinned batches of 8
  {
    const int r = tid>>2, p = tid&3;
    const float* srow = s + (size_t)(row0+r)*DD;
    const float* trow = t + (size_t)(row0+r)*DD;
    const int rf = r>>4, rl = r&15;
#pragma unroll
    for (int h=0; h<2; ++h){
      f32x4 va[8];
#pragma unroll
      for (int i=0;i<4;++i){
        int u = p + 4*(4*h + i);
        const float* pp = (u<16) ? (srow + 8*u) : (trow + 8*(u-16));
        va[2*i]   = __builtin_nontemporal_load((const f32x4*)pp);
        va[2*i+1] = __builtin_nontemporal_load((const f32x4*)(pp+4));
      }
      VMEM_FENCE();
#pragma unroll
      for (int i=0;i<4;++i){
        int u = p + 4*(4*h + i);
        short8 v = pack8(va[2*i], va[2*i+1]);
        *(short8*)(Xs + ((rf*8+(u>>2))*64 + (u&3)*16 + rl)*8) = v;
      }
    }
  }

  // level-0 zero-fills: hf f32 output (nt) + xsh hf-half (cached)
  if (row0 < MM){
    f32x4 zf4 = {0.f,0.f,0.f,0.f};
    short8 zs8 = {0,0,0,0,0,0,0,0};
    const size_t basei = (size_t)row0*DD;
    for (int i=tid; i<2048; i+=256)
      __builtin_nontemporal_store(zf4, (f32x4*)(hf + basei + i*4));
    for (int i=tid; i<1024; i+=256)
      *(short8*)(xsh + ((size_t)row0 + (i>>4))*256 + 128 + (i&15)*8) = zs8;
  }
  __syncthreads();

  f32x4 zf = {0.f,0.f,0.f,0.f};
  f32x4 acc[4][2];
#pragma unroll
  for (int rr=0;rr<4;++rr){ acc[rr][0]=zf; acc[rr][1]=zf; }
  const short* Aw = Wt + (16*w)*512 + lane*8;
#pragma unroll
  for (int h=0; h<2; ++h){
    short8 af[8];
#pragma unroll
    for (int i=0;i<8;++i) af[i] = *(const short8*)(Aw + (8*h + i)*512);
    VMEM_FENCE();
#pragma unroll
    for (int kc=0;kc<8;++kc){
      short8 bx[4];
#pragma unroll
      for (int rr=0;rr<4;++rr)
        bx[rr] = *(const short8*)(Xs + ((rr*8 + kc)*64 + lane)*8);
#pragma unroll
      for (int rr=0;rr<4;++rr)
        acc[rr][h] = MFMA16(af[kc], bx[rr], acc[rr][h]);
    }
  }

  f32x4 bv0 = *(const f32x4*)(b + 32*w + 4*lq);
  f32x4 bv1 = *(const f32x4*)(b + 32*w + 16 + 4*lq);
#pragma unroll
  for (int rr=0;rr<4;++rr){
    int row = row0 + rr*16 + l15;
#pragma unroll
    for (int q=0;q<2;++q){
      f32x4 bv = q ? bv1 : bv0;
      int col = 32*w + 16*q + 4*lq;
      f32x4 o; short4v pk;
#pragma unroll
      for (int j=0;j<4;++j){ o[j] = acc[rr][q][j] + bv[j]; pk[j] = f2bf(o[j]); }
      __builtin_nontemporal_store(o, (f32x4*)(hs + (size_t)row*DD + col));
      *(short4v*)(xsh + (size_t)row*256 + col) = pk;
    }
  }
}

// ---------------- fused per-level kernel: 32 nodes/block, col-split --------
// Gather: cached loads of ONE contiguous 512B xsh row (2x fanin reuse hits L2).
// XCD-aware bijective swizzle: same-gate (bucket-contiguous) blocks land on
// the same XCD -> each XCD's L2 holds only 1-2 gates' weights.
__global__ __launch_bounds__(256,5) void level_kernel(
    int lvl, float* __restrict__ hfg, short* __restrict__ xsh,
    const int* __restrict__ fanin,
    const short* __restrict__ W1t, const short* __restrict__ W2t,
    const short* __restrict__ W3t, const short* __restrict__ Wit,
    const float* __restrict__ b1, const float* __restrict__ b2,
    const float* __restrict__ b3, const float* __restrict__ bi,
    const float* __restrict__ bh,
    const int* __restrict__ off, const int* __restrict__ pend,
    const int* __restrict__ sorted)
{
  __shared__ __align__(16) short Xs[16384];      // 32768 B exactly
  const int tid=threadIdx.x, lane=tid&63, w=tid>>6;  // w = 0..3
  const int l15=lane&15, lq=lane>>4;
  const int li = lvl-1;

  // bijective XCD swizzle for nwg=1044 (q=130, r=4): XCD k gets a contiguous
  // chunk of bucket-sorted items (m204 formula).
  const int bid = blockIdx.x;
  const int xcd = bid & 7, idx = bid >> 3;
  const int nbid = ((xcd < 4) ? xcd*131 : 524 + (xcd-4)*130) + idx;
  const int pos0 = nbid*32;

  int g = -1;
#pragma unroll
  for (int q=0;q<GG;++q)
    if (pos0 >= off[li*GG+q] && pos0 < pend[li*GG+q]) g = q;
  if (g < 0) return;                              // uniform

  const int m0 = sorted[li*SORT_STRIDE + pos0 + l15];
  const int m1 = sorted[li*SORT_STRIDE + pos0 + 16 + l15];
  f32x4 zf = {0.f,0.f,0.f,0.f};

  // gather X rows (contiguous 512B per src row, CACHED) into fragment layout
  {
    const int r = tid>>2, p = tid&3;
    const int mg = sorted[li*SORT_STRIDE + pos0 + (r>>1)];
    const int src = (mg>=0) ? li*MM + fanin[((size_t)li*MM+mg)*FF + (r&1)] : 0;
    const short* xrow = xsh + (size_t)src*256;
    const int rf = r>>4, rl = r&15;
    const bool lvl1 = (lvl == 1);
    short8 va[8];
    short8 zs8 = {0,0,0,0,0,0,0,0};
#pragma unroll
    for (int i=0;i<8;++i){
      int u = p + 4*i;
      va[i] = (lvl1 && u >= 16) ? zs8 : *(const short8*)(xrow + 8*u);
    }
    VMEM_FENCE();
#pragma unroll
    for (int i=0;i<8;++i){
      int u = p + 4*i;
      *(short8*)(Xs + ((rf*8+(u>>2))*64 + (u&3)*16 + rl)*8) = va[i];
    }
  }
  __syncthreads();                                // B1

  // ---- GEMM1: K=256, A in two pinned batches of 8 ----
  f32x4 acc[4][2];
#pragma unroll
  for (int rr=0;rr<4;++rr){ acc[rr][0]=zf; acc[rr][1]=zf; }
  {
    const short* A1w = W1t + (size_t)g*32768 + (16*w)*512 + lane*8;
#pragma unroll
    for (int h=0; h<2; ++h){
      short8 af[8];
#pragma unroll
      for (int i=0;i<8;++i) af[i] = *(const short8*)(A1w + (8*h + i)*512);
      VMEM_FENCE();
#pragma unroll
      for (int kc=0;kc<8;++kc){
        short8 bx[4];
#pragma unroll
        for (int rr=0;rr<4;++rr)
          bx[rr] = *(const short8*)(Xs + ((rr*8 + kc)*64 + lane)*8);
#pragma unroll
        for (int rr=0;rr<4;++rr)
          acc[rr][h] = MFMA16(af[kc], bx[rr], acc[rr][h]);
      }
    }
  }
  __syncthreads();                                // B2: all X reads done
  {
    f32x4 bv0 = *(const f32x4*)(b1 + g*DD + 32*w + 4*lq);
    f32x4 bv1 = *(const f32x4*)(b1 + g*DD + 32*w + 16 + 4*lq);
#pragma unroll
    for (int rr=0;rr<4;++rr){
#pragma unroll
      for (int q=0;q<2;++q){
        f32x4 bv = q ? bv1 : bv0;
        short4v pk;
#pragma unroll
        for (int j=0;j<4;++j) pk[j] = f2bf(fmaxf(acc[rr][q][j] + bv[j], 0.f));
        *(short4v*)(Xs + ((rr*4 + w)*64 + (2*q + (lq>>1))*16 + l15)*8 + 4*(lq&1)) = pk;
      }
    }
  }
  __syncthreads();                                // B3: H1 ready

  // ---- GEMM2: K=128 ----
  f32x4 acc2[4][2];
#pragma unroll
  for (int rr=0;rr<4;++rr){ acc2[rr][0]=zf; acc2[rr][1]=zf; }
  {
    const short* A2w = W2t + (size_t)g*16384 + (8*w)*512 + lane*8;
    short8 af[8];
#pragma unroll
    for (int i=0;i<8;++i) af[i] = *(const short8*)(A2w + i*512);
    VMEM_FENCE();
#pragma unroll
    for (int kc=0;kc<4;++kc){
      short8 bx[4];
#pragma unroll
      for (int rr=0;rr<4;++rr)
        bx[rr] = *(const short8*)(Xs + ((rr*4 + kc)*64 + lane)*8);
#pragma unroll
      for (int rr=0;rr<4;++rr){
        acc2[rr][0] = MFMA16(af[kc],   bx[rr], acc2[rr][0]);
        acc2[rr][1] = MFMA16(af[4+kc], bx[rr], acc2[rr][1]);
      }
    }
  }
  {
    f32x4 bv0 = *(const f32x4*)(b2 + g*DD + 32*w + 4*lq);
    f32x4 bv1 = *(const f32x4*)(b2 + g*DD + 32*w + 16 + 4*lq);
#pragma unroll
    for (int rr=0;rr<4;++rr){
#pragma unroll
      for (int q=0;q<2;++q){
        f32x4 bv = q ? bv1 : bv0;
        short4v pk;
#pragma unroll
        for (int j=0;j<4;++j) pk[j] = f2bf(fmaxf(acc2[rr][q][j] + bv[j], 0.f));
        *(short4v*)(Xs + 8192 + ((rr*4 + w)*64 + (2*q + (lq>>1))*16 + l15)*8 + 4*(lq&1)) = pk;
      }
    }
  }
  __syncthreads();                                // B4: H2 ready

  // ---- GEMM3: K=128 ----
  f32x4 acc3[4][2];
#pragma unroll
  for (int rr=0;rr<4;++rr){ acc3[rr][0]=zf; acc3[rr][1]=zf; }
  {
    const short* A3w = W3t + (size_t)g*16384 + (8*w)*512 + lane*8;
    short8 af[8];
#pragma unroll
    for (int i=0;i<8;++i) af[i] = *(const short8*)(A3w + i*512);
    VMEM_FENCE();
#pragma unroll
    for (int kc=0;kc<4;++kc){
      short8 bx[4];
#pragma unroll
      for (int rr=0;rr<4;++rr)
        bx[rr] = *(const short8*)(Xs + 8192 + ((rr*4 + kc)*64 + lane)*8);
#pragma unroll
      for (int rr=0;rr<4;++rr){
        acc3[rr][0] = MFMA16(af[kc],   bx[rr], acc3[rr][0]);
        acc3[rr][1] = MFMA16(af[4+kc], bx[rr], acc3[rr][1]);
      }
    }
  }
  // pair-sum over F -> msg into Xs[0:4096)
  {
    f32x4 bv0 = *(const f32x4*)(b3 + g*DD + 32*w + 4*lq);
    f32x4 bv1 = *(const f32x4*)(b3 + g*DD + 32*w + 16 + 4*lq);
#pragma unroll
    for (int rr=0;rr<4;++rr){
#pragma unroll
      for (int q=0;q<2;++q){
        f32x4 bv = q ? bv1 : bv0;
        f32x4 mv;
#pragma unroll
        for (int j=0;j<4;++j){
          float v = acc3[rr][q][j];
          mv[j] = v + __shfl_xor(v, 1) + 2.f*bv[j];
        }
        if ((l15 & 1) == 0){
          int n = rr*8 + (l15>>1);                 // node 0..31
          short4v pk;
#pragma unroll
          for (int j=0;j<4;++j) pk[j] = f2bf(mv[j]);
          *(short4v*)(Xs + (((n>>4)*4 + w)*64 + (2*q + (lq>>1))*16 + (n&15))*8 + 4*(lq&1)) = pk;
        }
      }
    }
  }
  __syncthreads();                                // B5: msg ready

  // ---- GRU: gi = msg(32x128) @ Wi[g]; h==0 so gh==bh. 2 q-passes ----
  const short* AW = Wit + (size_t)g*49152 + lane*8;
  const int lo = lvl*MM;
#pragma unroll
  for (int q=0;q<2;++q){
    short8 af[12];
#pragma unroll
    for (int kc=0;kc<4;++kc){
      int cti = ((2*w + q)*4 + kc)*512;
      af[kc]   = *(const short8*)(AW + cti);
      af[4+kc] = *(const short8*)(AW + 16384 + cti);
      af[8+kc] = *(const short8*)(AW + 32768 + cti);
    }
    VMEM_FENCE();
    f32x4 gr[2], gz[2], gn[2];
    gr[0]=zf; gr[1]=zf; gz[0]=zf; gz[1]=zf; gn[0]=zf; gn[1]=zf;
#pragma unroll
    for (int kc=0;kc<4;++kc){
#pragma unroll
      for (int rfm=0;rfm<2;++rfm){
        short8 bm = *(const short8*)(Xs + ((rfm*4 + kc)*64 + lane)*8);
        gr[rfm] = MFMA16(af[kc],   bm, gr[rfm]);
        gz[rfm] = MFMA16(af[4+kc], bm, gz[rfm]);
        gn[rfm] = MFMA16(af[8+kc], bm, gn[rfm]);
      }
    }
    int col = 32*w + 16*q + 4*lq;
    f32x4 biR = *(const f32x4*)(bi + g*384 + col);
    f32x4 biZ = *(const f32x4*)(bi + g*384 + 128 + col);
    f32x4 biN = *(const f32x4*)(bi + g*384 + 256 + col);
    f32x4 bhR = *(const f32x4*)(bh + g*384 + col);
    f32x4 bhZ = *(const f32x4*)(bh + g*384 + 128 + col);
    f32x4 bhN = *(const f32x4*)(bh + g*384 + 256 + col);
#pragma unroll
    for (int rfm=0;rfm<2;++rfm){
      int m = rfm ? m1 : m0;
      if (m < 0) continue;
      f32x4 o; short4v pk;
#pragma unroll
      for (int j=0;j<4;++j){
        float xr = gr[rfm][j] + biR[j] + bhR[j];
        float xz = gz[rfm][j] + biZ[j] + bhZ[j];
        float r_ = 1.f/(1.f + __expf(-xr));
        float z_ = 1.f/(1.f + __expf(-xz));
        float xn = gn[rfm][j] + biN[j] + r_*bhN[j];
        float n_ = 2.f/(1.f + __expf(-2.f*xn)) - 1.f;
        o[j] = (1.f - z_)*n_;
        pk[j] = f2bf(o[j]);
      }
      __builtin_nontemporal_store(o, (f32x4*)(hfg + (size_t)(lo + m)*DD + col));
      *(short4v*)(xsh + (size_t)(lo + m)*256 + 128 + col) = pk;
    }
  }
}

extern "C" void kernel_launch(void* const* d_in, const int* in_sizes, int n_in,
                              void* d_out, int out_size, void* d_ws, size_t ws_size,
                              hipStream_t stream)
{
  const float* s    = (const float*)d_in[0];
  const float* t    = (const float*)d_in[1];
  const int*   gate = (const int*)d_in[2];
  const int*   fanin= (const int*)d_in[3];
  const float* hs_W = (const float*)d_in[4];
  const float* hs_b = (const float*)d_in[5];
  const float* W1   = (const float*)d_in[6];
  const float* b1   = (const float*)d_in[7];
  const float* W2   = (const float*)d_in[8];
  const float* b2   = (const float*)d_in[9];
  const float* W3   = (const float*)d_in[10];
  const float* b3   = (const float*)d_in[11];
  const float* Wi   = (const float*)d_in[12];
  // d_in[13] = gru_Wh: unused (hidden state is exactly zero)
  const float* bi   = (const float*)d_in[14];
  const float* bh   = (const float*)d_in[15];

  float* hs = (float*)d_out;
  float* hf = hs + (size_t)NN*DD;

  int* cnt    = (int*)d_ws;        // [7][5] ; cur right after
  int* cur    = cnt + 35;
  int* off    = cnt + 70;
  int* pendv  = cnt + 105;
  int* sorted = cnt + 256;         // 7*SORT_STRIDE ints, < 1 MB

  short* wbase = (short*)((char*)d_ws + (1<<20));
  short* hsWt = wbase;             // 4096*8
  short* W1t  = wbase + 32768;     // 5*32768
  short* W2t  = wbase + 196608;    // 5*16384
  short* W3t  = wbase + 278528;    // 5*16384
  short* Wit  = wbase + 360448;    // 5*49152

  // interleaved shadow: xsh[node][256] = [hs bf16 x128 | hf bf16 x128], 128MB
  short* xsh = (short*)((char*)d_ws + (size_t)(8<<20));

  prep_kernel<<<296, 256, 0, stream>>>(hs_W, W1, W2, W3, Wi,
                                       hsWt, W1t, W2t, W3t, Wit, cnt);
  count_kernel<<<896, 256, 0, stream>>>(gate, cnt);
  offs_kernel<<<1, 256, 0, stream>>>(cnt, off, pendv, sorted);
  scatter_kernel<<<896, 256, 0, stream>>>(gate, off, cur, sorted);
  hs_kernel<<<NN/64, 256, 0, stream>>>(s, t, hsWt, hs_b, hs, xsh, hf);
  for (int lvl = 1; lvl < LL; ++lvl){
    level_kernel<<<SORT_STRIDE/32, 256, 0, stream>>>(lvl, hf, xsh,
        fanin, W1t, W2t, W3t, Wit,
        b1, b2, b3, bi, bh, off, pendv, sorted);
  }
}